// Round 8
// baseline (557.322 us; speedup 1.0000x reference)
//
#include <hip/hip_runtime.h>
#include <hip/hip_bf16.h>
#include <math.h>

#define BB 8
#define CCH 256
#define HWN 4096
#define RR 16

typedef __attribute__((ext_vector_type(8))) short short8;   // 8 bf16 = K=32 MFMA A/B frag (4 VGPRs)
typedef __attribute__((ext_vector_type(4))) float f32x4;    // MFMA C/D frag

static __device__ __forceinline__ unsigned short f2bf(float x) {
    union { float f; unsigned u; } v; v.f = x;
    return (unsigned short)((v.u + 0x8000u) >> 16);   // round-half-up bf16
}
static __device__ __forceinline__ unsigned bfr(float x) {   // bits + rounding offset
    union { float f; unsigned u; } v; v.f = x;
    return v.u + 0x8000u;
}

// ---------------- K1: avg+max pool over spatial, per (b,c) ----------------
__global__ __launch_bounds__(256) void k_pool(const float* __restrict__ x,
                                              float* __restrict__ avgp,
                                              float* __restrict__ maxp) {
    int bc = blockIdx.x;
    const float4* p = (const float4*)(x + (size_t)bc * HWN);
    int t = threadIdx.x;
    float s = 0.f, m = -INFINITY;
#pragma unroll
    for (int i = 0; i < 4; ++i) {
        float4 v = p[t + 256 * i];
        s += v.x + v.y + v.z + v.w;
        m = fmaxf(m, fmaxf(fmaxf(v.x, v.y), fmaxf(v.z, v.w)));
    }
    for (int off = 32; off; off >>= 1) {
        s += __shfl_down(s, off);
        m = fmaxf(m, __shfl_down(m, off));
    }
    __shared__ float ss[4], sm[4];
    int wid = t >> 6;
    if ((t & 63) == 0) { ss[wid] = s; sm[wid] = m; }
    __syncthreads();
    if (t == 0) {
        float S = ss[0] + ss[1] + ss[2] + ss[3];
        float M = fmaxf(fmaxf(sm[0], sm[1]), fmaxf(sm[2], sm[3]));
        avgp[bc] = S * (1.f / (float)HWN);
        maxp[bc] = M;
    }
}

// ---------------- K2: SE gate ----------------
__global__ __launch_bounds__(256) void k_gate(const float* __restrict__ avgp,
                                              const float* __restrict__ maxp,
                                              const float* __restrict__ w1,
                                              const float* __restrict__ w2,
                                              float* __restrict__ gate) {
    int b = blockIdx.x, t = threadIdx.x;
    __shared__ float sa[CCH], sx[CCH], sh[32];
    sa[t] = avgp[b * CCH + t];
    sx[t] = maxp[b * CCH + t];
    __syncthreads();
    if (t < 32) {
        int r = t & 15;
        const float* src = (t < 16) ? sa : sx;
        float h = 0.f;
        for (int c = 0; c < CCH; ++c) h += w1[r * CCH + c] * src[c];
        sh[t] = fmaxf(h, 0.f);
    }
    __syncthreads();
    float g = 0.f;
#pragma unroll
    for (int r = 0; r < RR; ++r) g += w2[t * RR + r] * (sh[r] + sh[16 + r]);
    gate[b * CCH + t] = 1.f / (1.f + __expf(-g));
}

// ---------------- K-wprep: pack [vw;qw;kw] -> Wb bf16 [288][256] ----------------
__global__ __launch_bounds__(256) void k_wprep(const float* __restrict__ vw,
                                               const float* __restrict__ qw,
                                               const float* __restrict__ kw,
                                               unsigned short* __restrict__ Wb) {
    int idx = blockIdx.x * 256 + threadIdx.x;   // 288*256 = 73728
    int m = idx >> 8, c = idx & 255;
    float v;
    if (m < 256) v = vw[idx];
    else if (m < 272) v = qw[(m - 256) * 256 + c];
    else v = kw[(m - 272) * 256 + c];
    Wb[idx] = f2bf(v);
}

// ---------------- K-proj: fused q,k,v projections via bf16 MFMA ----------------
// vB in CHUNKED layout, natural j order: vB[b][jc][c][jo], jc = j>>3, jo = j&7.
__global__ __launch_bounds__(256) void k_proj(const float* __restrict__ x,
                                              const float* __restrict__ gate,
                                              const unsigned short* __restrict__ Wb,
                                              const float* __restrict__ vb,
                                              const float* __restrict__ qb,
                                              const float* __restrict__ kb,
                                              unsigned short* __restrict__ qT,
                                              unsigned short* __restrict__ kT,
                                              unsigned short* __restrict__ vB) {
    int b = blockIdx.x & 7;              // XCD swizzle: batch <-> XCD
    int n0 = (blockIdx.x >> 3) << 6;
    int t = threadIdx.x;
    int w = t >> 6, l = t & 63, quad = l >> 4, ln = l & 15;

    __shared__ __align__(16) unsigned short xs_t[64][72];    // [n_local][c_local] bf16
    __shared__ __align__(16) unsigned short vtile[256 * 72]; // [m][n_local] bf16, stride 72
    __shared__ float qk_s[32][66];   // q rows 0..15, k rows 16..31 (fp32)

    const f32x4 zf = {0.f, 0.f, 0.f, 0.f};
    f32x4 acc[18];
#pragma unroll
    for (int mt = 0; mt < 18; ++mt) acc[mt] = zf;

    for (int cc = 0; cc < 4; ++cc) {
        __syncthreads();
#pragma unroll
        for (int it = 0; it < 4; ++it) {
            int idx = it * 256 + t;
            int cl = idx >> 4, nq = idx & 15;
            int c = cc * 64 + cl;
            float g = gate[b * CCH + c];
            float4 v = *(const float4*)(x + (((size_t)(b * CCH + c)) << 12) + n0 + nq * 4);
            xs_t[nq * 4 + 0][cl] = f2bf(v.x * g);
            xs_t[nq * 4 + 1][cl] = f2bf(v.y * g);
            xs_t[nq * 4 + 2][cl] = f2bf(v.z * g);
            xs_t[nq * 4 + 3][cl] = f2bf(v.w * g);
        }
        __syncthreads();

        short8 bfrag[2];
#pragma unroll
        for (int kc = 0; kc < 2; ++kc)
            bfrag[kc] = *(const short8*)&xs_t[w * 16 + ln][kc * 32 + quad * 8];

#pragma unroll
        for (int mt = 0; mt < 18; ++mt) {
#pragma unroll
            for (int kc = 0; kc < 2; ++kc) {
                short8 af = *(const short8*)(Wb + ((size_t)(mt * 16 + ln)) * 256 + cc * 64 + kc * 32 + quad * 8);
                acc[mt] = __builtin_amdgcn_mfma_f32_16x16x32_bf16(af, bfrag[kc], acc[mt], 0, 0, 0);
            }
        }
    }

    // v rows -> vtile[m][n_local]
#pragma unroll
    for (int mt = 0; mt < 16; ++mt) {
#pragma unroll
        for (int r = 0; r < 4; ++r) {
            int m = mt * 16 + quad * 4 + r;
            vtile[m * 72 + w * 16 + ln] = f2bf(acc[mt][r] + vb[m]);
        }
    }
    // q/k -> LDS for transpose
#pragma unroll
    for (int r = 0; r < 4; ++r) {
        qk_s[quad * 4 + r][w * 16 + ln] = acc[16][r];
        qk_s[16 + quad * 4 + r][w * 16 + ln] = acc[17][r];
    }
    __syncthreads();

    // stream vtile -> vB chunks: thread t = c; 8 x 16B stores, 1KB coalesced segments
    {
        unsigned short* vBp = vB + (((size_t)b) << 20);
        int c = t;
#pragma unroll
        for (int Q = 0; Q < 8; ++Q) {
            short8 v8 = *(const short8*)(vtile + c * 72 + Q * 8);
            *(short8*)(vBp + ((size_t)((((n0 >> 3) + Q) << 8) + c) << 3)) = v8;
        }
    }
    if (t < 128) {
        int isK = t >> 6;
        int n = t & 63;
        const float* bias = isK ? kb : qb;
        unsigned u32[8];
#pragma unroll
        for (int j = 0; j < 8; ++j) {
            unsigned lo = f2bf(qk_s[isK * 16 + 2 * j][n] + bias[2 * j]);
            unsigned hi = f2bf(qk_s[isK * 16 + 2 * j + 1][n] + bias[2 * j + 1]);
            u32[j] = lo | (hi << 16);
        }
        unsigned short* dst = (isK ? kT : qT) + ((size_t)(b * HWN + n0 + n)) * RR;
        uint4 d0 = {u32[0], u32[1], u32[2], u32[3]};
        uint4 d1 = {u32[4], u32[5], u32[6], u32[7]};
        ((uint4*)dst)[0] = d0;
        ((uint4*)dst)[1] = d1;
    }
}

// ---------------- K-attn: MFMA flash attention, 4-wave blocks, fine-grain residency ----
// R8: block = (b XCD-swizzled, 16-i tile), 256 threads = 4 waves, grid 8x256 = 2048
// (8 blocks/CU available). Wave w: S^T for j-subtile w (16j x 16i, ONE MFMA, A=K B=Q);
// PV c-range w*64 (4cs x 2ks = 8 MFMAs). P in XOR-SWIZZLED LDS (PSTR=64, no pad):
// 16B-chunk index C ^= (row&7) -> store = uniform 4/bank, b128 read = uniform 8/bank,
// both minimum-cycle (fixes R7's 1.05e7 conflicts from PSTR=72). V single-buffered
// (-32 VGPR), K double-buffered; ~75 total regs -> ~6 waves/SIMD.
__global__ __launch_bounds__(256, 6) void k_attn(const unsigned short* __restrict__ qT,
                                                 const unsigned short* __restrict__ kT,
                                                 const unsigned short* __restrict__ vB,
                                                 const float* __restrict__ x,
                                                 const float* __restrict__ gate,
                                                 const float* __restrict__ gamma,
                                                 float* __restrict__ out) {
    int b = blockIdx.x & 7;
    int i0 = (blockIdx.x >> 3) << 4;     // 16-i tile
    int t = threadIdx.x;
    int w = t >> 6, l = t & 63;
    int quad = l >> 4, ln = l & 15;
    int c0 = w * 64;

    __shared__ __align__(16) unsigned short p_lds[2][16 * 64];   // swizzled, 4KB total
    __shared__ float l_s[4][20];

    const short8 zs = {0, 0, 0, 0, 0, 0, 0, 0};
    const f32x4 zf = {0.f, 0.f, 0.f, 0.f};

    // persistent Q B-frag: B[k=d=quad*8+kk][n=i=ln] (quads 2,3 zero-pad d 16..31)
    short8 bq = zs;
    if (quad < 2)
        bq = *(const short8*)(qT + (((size_t)(b * HWN + i0 + ln)) << 4) + (quad << 3));

    f32x4 acc[4];
#pragma unroll
    for (int cs = 0; cs < 4; ++cs) acc[cs] = zf;
    float lsum = 0.f;

    const float c1 = 1.44269504f;      // log2(e)
    const float c0e = -11.5415603f;    // -8*log2(e): fixed shift, cancels in p/l

    const unsigned short* vbase = vB + (((size_t)b) << 20) + ((size_t)c0 << 3);
    const unsigned short* kbase = kT + ((size_t)(b * HWN)) * RR;

    // hoisted swizzled LDS offsets (key = ln&7, consistent store/read per row=ln)
    int key = ln & 7;
    int soff = ln * 64 + (((w * 2 + (quad >> 1)) ^ key) * 2 + (quad & 1)) * 4;  // uint2 store
    int roff0 = ln * 64 + ((quad ^ key) << 3);          // ks=0 b128 read
    int roff1 = ln * 64 + (((4 + quad) ^ key) << 3);    // ks=1

    short8 akA = zs, akB = zs;          // K A-frag dbuf: A[m=j][k=d]
    short8 av[8];                       // V A-frags [ks*4+cs], SINGLE buffer

    auto load_ak = [&](short8& ak, int j0) {
        if (quad < 2)
            ak = *(const short8*)(kbase + (((size_t)(j0 + w * 16 + ln)) << 4) + (quad << 3));
    };
    auto load_av = [&](int j0) {
#pragma unroll
        for (int ks = 0; ks < 2; ++ks)
#pragma unroll
            for (int cs = 0; cs < 4; ++cs) {
                int jc = (j0 >> 3) + ks * 4 + quad;
                av[ks * 4 + cs] = *(const short8*)(vbase + ((size_t)(((jc << 8) + cs * 16 + ln)) << 3));
            }
    };
    auto sstep = [&](short8& akC, unsigned short* pbuf) {
        // S^T: C[row = j_local = quad*4+r][col = i = ln]
        f32x4 sf = __builtin_amdgcn_mfma_f32_16x16x32_bf16(akC, bq, zf, 0, 0, 0);
        float p0 = exp2f(fmaf(sf[0], c1, c0e));
        float p1 = exp2f(fmaf(sf[1], c1, c0e));
        float p2 = exp2f(fmaf(sf[2], c1, c0e));
        float p3 = exp2f(fmaf(sf[3], c1, c0e));
        lsum += (p0 + p1) + (p2 + p3);
        uint2 pk;
        pk.x = (bfr(p0) >> 16) | (bfr(p1) & 0xFFFF0000u);
        pk.y = (bfr(p2) >> 16) | (bfr(p3) & 0xFFFF0000u);
        *(uint2*)(pbuf + soff) = pk;
    };
    auto pvstep = [&](const unsigned short* pbuf) {
        short8 bp0 = *(const short8*)(pbuf + roff0);
#pragma unroll
        for (int cs = 0; cs < 4; ++cs)
            acc[cs] = __builtin_amdgcn_mfma_f32_16x16x32_bf16(av[cs], bp0, acc[cs], 0, 0, 0);
        short8 bp1 = *(const short8*)(pbuf + roff1);
#pragma unroll
        for (int cs = 0; cs < 4; ++cs)
            acc[cs] = __builtin_amdgcn_mfma_f32_16x16x32_bf16(av[4 + cs], bp1, acc[cs], 0, 0, 0);
    };

    load_ak(akA, 0);
    load_av(0);

    for (int jt2 = 0; jt2 < 32; ++jt2) {
        int j0 = jt2 << 7;
        // even step (akA, P buf 0)
        sstep(akA, &p_lds[0][0]);
        __syncthreads();
        load_ak(akB, j0 + 64);     // next K: covered by pvstep+sstep below
        pvstep(&p_lds[0][0]);      // consumes av(j0)
        load_av(j0 + 64);          // next V: single buf, loaded after consume

        // odd step (akB, P buf 1)
        int j0n = (jt2 < 31) ? (j0 + 128) : 0;   // clamp on last iter (loads discarded)
        sstep(akB, &p_lds[1][0]);
        __syncthreads();
        load_ak(akA, j0n);
        pvstep(&p_lds[1][0]);
        load_av(j0n);
    }

    // l: lane covers j = w*16+quad*4..+4 for i=ln -> reduce over quads, then waves
    lsum += __shfl_xor(lsum, 16, 64);
    lsum += __shfl_xor(lsum, 32, 64);
    if (l < 16) l_s[w][l] = lsum;
    __syncthreads();

    float g = gamma[0];
    float lf = (l_s[0][ln] + l_s[1][ln]) + (l_s[2][ln] + l_s[3][ln]);
    float rinv = g / lf;

    // epilogue: out = gamma*o/l + x*gate
#pragma unroll
    for (int cs = 0; cs < 4; ++cs) {
#pragma unroll
        for (int r = 0; r < 4; ++r) {
            int c = c0 + cs * 16 + quad * 4 + r;
            float gc = gate[b * CCH + c];
            size_t rowoff = (((size_t)(b * CCH + c)) << 12) + i0;
            out[rowoff + ln] = acc[cs][r] * rinv + x[rowoff + ln] * gc;
        }
    }
}

extern "C" void kernel_launch(void* const* d_in, const int* in_sizes, int n_in,
                              void* d_out, int out_size, void* d_ws, size_t ws_size,
                              hipStream_t stream) {
    const float* x = (const float*)d_in[0];
    const float* w1 = (const float*)d_in[1];
    const float* w2 = (const float*)d_in[2];
    const float* qw = (const float*)d_in[3];
    const float* qb = (const float*)d_in[4];
    const float* kw = (const float*)d_in[5];
    const float* kb = (const float*)d_in[6];
    const float* vw = (const float*)d_in[7];
    const float* vb = (const float*)d_in[8];
    const float* gamma = (const float*)d_in[9];
    float* out = (float*)d_out;
    char* ws = (char*)d_ws;

    float* avgp = (float*)(ws);                        // 8 KB
    float* maxp = (float*)(ws + 8192);                 // 8 KB
    float* gate = (float*)(ws + 16384);                // 8 KB
    unsigned short* Wb = (unsigned short*)(ws + 24576);               // [288][256] bf16
    unsigned short* qT = (unsigned short*)(ws + 24576 + 147456);      // 1 MB [b][n][16]
    unsigned short* kT = (unsigned short*)(ws + 24576 + 147456 + 1048576);
    unsigned short* vB = (unsigned short*)(ws + 24576 + 147456 + 2097152);  // 16.8 MB chunked

    k_pool<<<2048, 256, 0, stream>>>(x, avgp, maxp);
    k_wprep<<<288, 256, 0, stream>>>(vw, qw, kw, Wb);
    k_gate<<<8, 256, 0, stream>>>(avgp, maxp, w1, w2, gate);
    k_proj<<<512, 256, 0, stream>>>(x, gate, Wb, vb, qb, kb, qT, kT, vB);
    k_attn<<<2048, 256, 0, stream>>>(qT, kT, vB, x, gate, gamma, out);
}

// Round 9
// 403.512 us; speedup vs baseline: 1.3812x; 1.3812x over previous
//
#include <hip/hip_runtime.h>
#include <hip/hip_bf16.h>
#include <math.h>

#define BB 8
#define CCH 256
#define HWN 4096
#define RR 16
#define PSTR 68   // p_lds ushort row stride (136B): measured conflict-free (R5) for uint2 store + b128 read

typedef __attribute__((ext_vector_type(8))) short short8;   // 8 bf16 = K=32 MFMA A/B frag (4 VGPRs)
typedef __attribute__((ext_vector_type(4))) float f32x4;    // MFMA C/D frag

static __device__ __forceinline__ unsigned short f2bf(float x) {
    union { float f; unsigned u; } v; v.f = x;
    return (unsigned short)((v.u + 0x8000u) >> 16);   // round-half-up bf16
}
static __device__ __forceinline__ unsigned bfr(float x) {   // bits + rounding offset
    union { float f; unsigned u; } v; v.f = x;
    return v.u + 0x8000u;
}

// ---------------- K1: avg+max pool over spatial, per (b,c) ----------------
__global__ __launch_bounds__(256) void k_pool(const float* __restrict__ x,
                                              float* __restrict__ avgp,
                                              float* __restrict__ maxp) {
    int bc = blockIdx.x;
    const float4* p = (const float4*)(x + (size_t)bc * HWN);
    int t = threadIdx.x;
    float s = 0.f, m = -INFINITY;
#pragma unroll
    for (int i = 0; i < 4; ++i) {
        float4 v = p[t + 256 * i];
        s += v.x + v.y + v.z + v.w;
        m = fmaxf(m, fmaxf(fmaxf(v.x, v.y), fmaxf(v.z, v.w)));
    }
    for (int off = 32; off; off >>= 1) {
        s += __shfl_down(s, off);
        m = fmaxf(m, __shfl_down(m, off));
    }
    __shared__ float ss[4], sm[4];
    int wid = t >> 6;
    if ((t & 63) == 0) { ss[wid] = s; sm[wid] = m; }
    __syncthreads();
    if (t == 0) {
        float S = ss[0] + ss[1] + ss[2] + ss[3];
        float M = fmaxf(fmaxf(sm[0], sm[1]), fmaxf(sm[2], sm[3]));
        avgp[bc] = S * (1.f / (float)HWN);
        maxp[bc] = M;
    }
}

// ---------------- K2: SE gate ----------------
__global__ __launch_bounds__(256) void k_gate(const float* __restrict__ avgp,
                                              const float* __restrict__ maxp,
                                              const float* __restrict__ w1,
                                              const float* __restrict__ w2,
                                              float* __restrict__ gate) {
    int b = blockIdx.x, t = threadIdx.x;
    __shared__ float sa[CCH], sx[CCH], sh[32];
    sa[t] = avgp[b * CCH + t];
    sx[t] = maxp[b * CCH + t];
    __syncthreads();
    if (t < 32) {
        int r = t & 15;
        const float* src = (t < 16) ? sa : sx;
        float h = 0.f;
        for (int c = 0; c < CCH; ++c) h += w1[r * CCH + c] * src[c];
        sh[t] = fmaxf(h, 0.f);
    }
    __syncthreads();
    float g = 0.f;
#pragma unroll
    for (int r = 0; r < RR; ++r) g += w2[t * RR + r] * (sh[r] + sh[16 + r]);
    gate[b * CCH + t] = 1.f / (1.f + __expf(-g));
}

// ---------------- K-wprep: pack [vw;qw;kw] -> Wb bf16 [288][256] ----------------
__global__ __launch_bounds__(256) void k_wprep(const float* __restrict__ vw,
                                               const float* __restrict__ qw,
                                               const float* __restrict__ kw,
                                               unsigned short* __restrict__ Wb) {
    int idx = blockIdx.x * 256 + threadIdx.x;   // 288*256 = 73728
    int m = idx >> 8, c = idx & 255;
    float v;
    if (m < 256) v = vw[idx];
    else if (m < 272) v = qw[(m - 256) * 256 + c];
    else v = kw[(m - 272) * 256 + c];
    Wb[idx] = f2bf(v);
}

// ---------------- K-proj: fused q,k,v projections via bf16 MFMA ----------------
// vB in CHUNKED layout, natural j order: vB[b][jc][c][jo], jc = j>>3, jo = j&7.
__global__ __launch_bounds__(256) void k_proj(const float* __restrict__ x,
                                              const float* __restrict__ gate,
                                              const unsigned short* __restrict__ Wb,
                                              const float* __restrict__ vb,
                                              const float* __restrict__ qb,
                                              const float* __restrict__ kb,
                                              unsigned short* __restrict__ qT,
                                              unsigned short* __restrict__ kT,
                                              unsigned short* __restrict__ vB) {
    int b = blockIdx.x & 7;              // XCD swizzle: batch <-> XCD
    int n0 = (blockIdx.x >> 3) << 6;
    int t = threadIdx.x;
    int w = t >> 6, l = t & 63, quad = l >> 4, ln = l & 15;

    __shared__ __align__(16) unsigned short xs_t[64][72];    // [n_local][c_local] bf16
    __shared__ __align__(16) unsigned short vtile[256 * 72]; // [m][n_local] bf16, stride 72
    __shared__ float qk_s[32][66];   // q rows 0..15, k rows 16..31 (fp32)

    const f32x4 zf = {0.f, 0.f, 0.f, 0.f};
    f32x4 acc[18];
#pragma unroll
    for (int mt = 0; mt < 18; ++mt) acc[mt] = zf;

    for (int cc = 0; cc < 4; ++cc) {
        __syncthreads();
#pragma unroll
        for (int it = 0; it < 4; ++it) {
            int idx = it * 256 + t;
            int cl = idx >> 4, nq = idx & 15;
            int c = cc * 64 + cl;
            float g = gate[b * CCH + c];
            float4 v = *(const float4*)(x + (((size_t)(b * CCH + c)) << 12) + n0 + nq * 4);
            xs_t[nq * 4 + 0][cl] = f2bf(v.x * g);
            xs_t[nq * 4 + 1][cl] = f2bf(v.y * g);
            xs_t[nq * 4 + 2][cl] = f2bf(v.z * g);
            xs_t[nq * 4 + 3][cl] = f2bf(v.w * g);
        }
        __syncthreads();

        short8 bfrag[2];
#pragma unroll
        for (int kc = 0; kc < 2; ++kc)
            bfrag[kc] = *(const short8*)&xs_t[w * 16 + ln][kc * 32 + quad * 8];

#pragma unroll
        for (int mt = 0; mt < 18; ++mt) {
#pragma unroll
            for (int kc = 0; kc < 2; ++kc) {
                short8 af = *(const short8*)(Wb + ((size_t)(mt * 16 + ln)) * 256 + cc * 64 + kc * 32 + quad * 8);
                acc[mt] = __builtin_amdgcn_mfma_f32_16x16x32_bf16(af, bfrag[kc], acc[mt], 0, 0, 0);
            }
        }
    }

    // v rows -> vtile[m][n_local]
#pragma unroll
    for (int mt = 0; mt < 16; ++mt) {
#pragma unroll
        for (int r = 0; r < 4; ++r) {
            int m = mt * 16 + quad * 4 + r;
            vtile[m * 72 + w * 16 + ln] = f2bf(acc[mt][r] + vb[m]);
        }
    }
    // q/k -> LDS for transpose
#pragma unroll
    for (int r = 0; r < 4; ++r) {
        qk_s[quad * 4 + r][w * 16 + ln] = acc[16][r];
        qk_s[16 + quad * 4 + r][w * 16 + ln] = acc[17][r];
    }
    __syncthreads();

    // stream vtile -> vB chunks: thread t = c; 8 x 16B stores, 1KB coalesced segments
    {
        unsigned short* vBp = vB + (((size_t)b) << 20);
        int c = t;
#pragma unroll
        for (int Q = 0; Q < 8; ++Q) {
            short8 v8 = *(const short8*)(vtile + c * 72 + Q * 8);
            *(short8*)(vBp + ((size_t)((((n0 >> 3) + Q) << 8) + c) << 3)) = v8;
        }
    }
    if (t < 128) {
        int isK = t >> 6;
        int n = t & 63;
        const float* bias = isK ? kb : qb;
        unsigned u32[8];
#pragma unroll
        for (int j = 0; j < 8; ++j) {
            unsigned lo = f2bf(qk_s[isK * 16 + 2 * j][n] + bias[2 * j]);
            unsigned hi = f2bf(qk_s[isK * 16 + 2 * j + 1][n] + bias[2 * j + 1]);
            u32[j] = lo | (hi << 16);
        }
        unsigned short* dst = (isK ? kT : qT) + ((size_t)(b * HWN + n0 + n)) * RR;
        uint4 d0 = {u32[0], u32[1], u32[2], u32[3]};
        uint4 d1 = {u32[4], u32[5], u32[6], u32[7]};
        ((uint4*)dst)[0] = d0;
        ((uint4*)dst)[1] = d1;
    }
}

// ---------------- K-attn: MFMA flash attention, i-tile 64, 8-wave blocks ----------------
// R9: i_tile is the L2-pressure knob (V L2 traffic = HW/i_tile x 2MB x 8), wave count the
// latency knob. R8 (i16) blew L2 (FETCH 580MB); R7 (i32) was fine but 2x the wave-steps.
// Block = (b XCD-swizzled, 64-i tile), 512 threads = 8 waves, grid 8x64=512 = 2 blocks/CU.
// Wave w: S^T for j-half (jw=w>>2)*32 x i-tile (iw=w&3)*16 = 2 MFMAs (A=K, B=Q);
// PV c-range w*32: 2cs x 4is x 2ks = 16 MFMAs. P via PSTR=68 LDS (R5-measured 0 conflicts).
// V single-buffered, K double-buffered, prefetch right after the barrier (full-step gap).
__global__ __launch_bounds__(512, 4) void k_attn(const unsigned short* __restrict__ qT,
                                                 const unsigned short* __restrict__ kT,
                                                 const unsigned short* __restrict__ vB,
                                                 const float* __restrict__ x,
                                                 const float* __restrict__ gate,
                                                 const float* __restrict__ gamma,
                                                 float* __restrict__ out) {
    int b = blockIdx.x & 7;
    int i0 = (blockIdx.x >> 3) << 6;     // 64-i tile
    int t = threadIdx.x;
    int w = t >> 6, l = t & 63;
    int quad = l >> 4, ln = l & 15;
    int iw = w & 3, jw = w >> 2;
    int c0 = w * 32;

    __shared__ __align__(16) unsigned short p_lds[2][64 * PSTR];   // 17.4 KB
    __shared__ float l_s[8][20];

    const short8 zs = {0, 0, 0, 0, 0, 0, 0, 0};
    const f32x4 zf = {0.f, 0.f, 0.f, 0.f};

    // persistent Q B-frag: B[k=d=quad*8+kk][n=i=iw*16+ln] (quads 2,3 zero-pad d 16..31)
    short8 bq = zs;
    if (quad < 2)
        bq = *(const short8*)(qT + (((size_t)(b * HWN + i0 + iw * 16 + ln)) << 4) + (quad << 3));

    f32x4 acc[2][4];   // [cs][is]
#pragma unroll
    for (int cs = 0; cs < 2; ++cs)
#pragma unroll
        for (int is = 0; is < 4; ++is) acc[cs][is] = zf;
    float lsum = 0.f;

    const float c1 = 1.44269504f;      // log2(e)
    const float c0e = -11.5415603f;    // -8*log2(e): fixed shift, cancels in p/l

    const unsigned short* vbase = vB + (((size_t)b) << 20) + ((size_t)c0 << 3);
    const unsigned short* kbase = kT + ((size_t)(b * HWN)) * RR;

    // hoisted LDS offsets: P row = i_local = iw*16+ln, col = jw*32 + jt*16 + quad*4
    int soff0 = (iw * 16 + ln) * PSTR + jw * 32 + quad * 4;
    int soff1 = soff0 + 16;

    short8 akA[2], akB[2];          // K A-frag dbuf: A[m=j][k=d], jt in {0,1}
    short8 av[4];                   // V A-frags [ks*2+cs], SINGLE buffer
#pragma unroll
    for (int jt = 0; jt < 2; ++jt) { akA[jt] = zs; akB[jt] = zs; }

    auto load_ak = [&](short8 (&ak)[2], int j0) {
        if (quad < 2) {
#pragma unroll
            for (int jt = 0; jt < 2; ++jt)
                ak[jt] = *(const short8*)(kbase + (((size_t)(j0 + jw * 32 + jt * 16 + ln)) << 4) + (quad << 3));
        }
    };
    auto load_av = [&](int j0) {
#pragma unroll
        for (int ks = 0; ks < 2; ++ks)
#pragma unroll
            for (int cs = 0; cs < 2; ++cs) {
                int jc = (j0 >> 3) + ks * 4 + quad;
                av[ks * 2 + cs] = *(const short8*)(vbase + ((size_t)(((jc << 8) + cs * 16 + ln)) << 3));
            }
    };
    auto sstep = [&](short8 (&akC)[2], unsigned short* pbuf) {
        // S^T: C[row = j_local = quad*4+r][col = i = iw*16+ln]
        f32x4 sf0 = __builtin_amdgcn_mfma_f32_16x16x32_bf16(akC[0], bq, zf, 0, 0, 0);
        f32x4 sf1 = __builtin_amdgcn_mfma_f32_16x16x32_bf16(akC[1], bq, zf, 0, 0, 0);
        float p0 = exp2f(fmaf(sf0[0], c1, c0e));
        float p1 = exp2f(fmaf(sf0[1], c1, c0e));
        float p2 = exp2f(fmaf(sf0[2], c1, c0e));
        float p3 = exp2f(fmaf(sf0[3], c1, c0e));
        float q0 = exp2f(fmaf(sf1[0], c1, c0e));
        float q1 = exp2f(fmaf(sf1[1], c1, c0e));
        float q2 = exp2f(fmaf(sf1[2], c1, c0e));
        float q3 = exp2f(fmaf(sf1[3], c1, c0e));
        lsum += ((p0 + p1) + (p2 + p3)) + ((q0 + q1) + (q2 + q3));
        uint2 pk;
        pk.x = (bfr(p0) >> 16) | (bfr(p1) & 0xFFFF0000u);
        pk.y = (bfr(p2) >> 16) | (bfr(p3) & 0xFFFF0000u);
        *(uint2*)(pbuf + soff0) = pk;
        uint2 qk;
        qk.x = (bfr(q0) >> 16) | (bfr(q1) & 0xFFFF0000u);
        qk.y = (bfr(q2) >> 16) | (bfr(q3) & 0xFFFF0000u);
        *(uint2*)(pbuf + soff1) = qk;
    };
    auto pvstep = [&](const unsigned short* pbuf) {
#pragma unroll
        for (int ks = 0; ks < 2; ++ks) {
            short8 bp[4];
#pragma unroll
            for (int is = 0; is < 4; ++is)
                bp[is] = *(const short8*)(pbuf + (is * 16 + ln) * PSTR + ks * 32 + quad * 8);
#pragma unroll
            for (int cs = 0; cs < 2; ++cs)
#pragma unroll
                for (int is = 0; is < 4; ++is)
                    acc[cs][is] = __builtin_amdgcn_mfma_f32_16x16x32_bf16(av[ks * 2 + cs], bp[is], acc[cs][is], 0, 0, 0);
        }
    };

    load_ak(akA, 0);
    load_av(0);

    for (int jt2 = 0; jt2 < 32; ++jt2) {
        int j0 = jt2 << 7;
        // even step (akA, P buf 0)
        sstep(akA, &p_lds[0][0]);
        __syncthreads();
        load_ak(akB, j0 + 64);     // next K: drained at next barrier, full step later
        pvstep(&p_lds[0][0]);      // consumes av(j0)
        load_av(j0 + 64);          // next V: single buf, loaded after consume

        // odd step (akB, P buf 1)
        int j0n = (jt2 < 31) ? (j0 + 128) : 0;   // clamp on last iter (loads discarded)
        sstep(akB, &p_lds[1][0]);
        __syncthreads();
        load_ak(akA, j0n);
        pvstep(&p_lds[1][0]);
        load_av(j0n);
    }

    // l: lane covers its i = iw*16+ln; reduce over quads (same i), then jw-halves
    lsum += __shfl_xor(lsum, 16, 64);
    lsum += __shfl_xor(lsum, 32, 64);
    if (l < 16) l_s[w][l] = lsum;
    __syncthreads();

    float g = gamma[0];
    float rinv[4];
#pragma unroll
    for (int is = 0; is < 4; ++is)
        rinv[is] = g / (l_s[is][ln] + l_s[is + 4][ln]);

    // epilogue: out = gamma*o/l + x*gate (256B contiguous per c-row over the is loop)
#pragma unroll
    for (int cs = 0; cs < 2; ++cs) {
#pragma unroll
        for (int r = 0; r < 4; ++r) {
            int c = c0 + cs * 16 + quad * 4 + r;
            float gc = gate[b * CCH + c];
            size_t rowoff = (((size_t)(b * CCH + c)) << 12) + i0;
            float* po = out + rowoff;
            const float* px = x + rowoff;
#pragma unroll
            for (int is = 0; is < 4; ++is) {
                int idx = is * 16 + ln;
                po[idx] = acc[cs][is][r] * rinv[is] + px[idx] * gc;
            }
        }
    }
}

extern "C" void kernel_launch(void* const* d_in, const int* in_sizes, int n_in,
                              void* d_out, int out_size, void* d_ws, size_t ws_size,
                              hipStream_t stream) {
    const float* x = (const float*)d_in[0];
    const float* w1 = (const float*)d_in[1];
    const float* w2 = (const float*)d_in[2];
    const float* qw = (const float*)d_in[3];
    const float* qb = (const float*)d_in[4];
    const float* kw = (const float*)d_in[5];
    const float* kb = (const float*)d_in[6];
    const float* vw = (const float*)d_in[7];
    const float* vb = (const float*)d_in[8];
    const float* gamma = (const float*)d_in[9];
    float* out = (float*)d_out;
    char* ws = (char*)d_ws;

    float* avgp = (float*)(ws);                        // 8 KB
    float* maxp = (float*)(ws + 8192);                 // 8 KB
    float* gate = (float*)(ws + 16384);                // 8 KB
    unsigned short* Wb = (unsigned short*)(ws + 24576);               // [288][256] bf16
    unsigned short* qT = (unsigned short*)(ws + 24576 + 147456);      // 1 MB [b][n][16]
    unsigned short* kT = (unsigned short*)(ws + 24576 + 147456 + 1048576);
    unsigned short* vB = (unsigned short*)(ws + 24576 + 147456 + 2097152);  // 16.8 MB chunked

    k_pool<<<2048, 256, 0, stream>>>(x, avgp, maxp);
    k_wprep<<<288, 256, 0, stream>>>(vw, qw, kw, Wb);
    k_gate<<<8, 256, 0, stream>>>(avgp, maxp, w1, w2, gate);
    k_proj<<<512, 256, 0, stream>>>(x, gate, Wb, vb, qb, kb, qT, kT, vB);
    k_attn<<<512, 512, 0, stream>>>(qT, kT, vB, x, gate, gamma, out);
}

// Round 10
// 387.907 us; speedup vs baseline: 1.4367x; 1.0402x over previous
//
#include <hip/hip_runtime.h>
#include <hip/hip_bf16.h>
#include <math.h>

#define BB 8
#define CCH 256
#define HWN 4096
#define RR 16
#define PSTR 68   // p_lds ushort row stride (136B): MEASURED conflict-free (R5/R9: SQ_LDS_BANK_CONFLICT=0)
                  // for this exact uint2-store / b128-read pattern. PSTR=72 measured 1.05e7 (R7).

typedef __attribute__((ext_vector_type(8))) short short8;   // 8 bf16 = K=32 MFMA A/B frag (4 VGPRs)
typedef __attribute__((ext_vector_type(4))) float f32x4;    // MFMA C/D frag

static __device__ __forceinline__ unsigned short f2bf(float x) {
    union { float f; unsigned u; } v; v.f = x;
    return (unsigned short)((v.u + 0x8000u) >> 16);   // round-half-up bf16
}
static __device__ __forceinline__ unsigned bfr(float x) {   // bits + rounding offset
    union { float f; unsigned u; } v; v.f = x;
    return v.u + 0x8000u;
}

// ---------------- K1: avg+max pool per (b,c); blocks 0..287 also pack Wb (fused k_wprep) ---
__global__ __launch_bounds__(256) void k_pool(const float* __restrict__ x,
                                              float* __restrict__ avgp,
                                              float* __restrict__ maxp,
                                              const float* __restrict__ vw,
                                              const float* __restrict__ qw,
                                              const float* __restrict__ kw,
                                              unsigned short* __restrict__ Wb) {
    int bc = blockIdx.x;
    int t = threadIdx.x;
    // fused weight-pack: [vw;qw;kw] -> Wb bf16 [288][256]
    if (bc < 288) {
        int idx = bc * 256 + t;
        int m = idx >> 8, c = idx & 255;
        float v;
        if (m < 256) v = vw[idx];
        else if (m < 272) v = qw[(m - 256) * 256 + c];
        else v = kw[(m - 272) * 256 + c];
        Wb[idx] = f2bf(v);
    }
    const float4* p = (const float4*)(x + (size_t)bc * HWN);
    float s = 0.f, m = -INFINITY;
#pragma unroll
    for (int i = 0; i < 4; ++i) {
        float4 v = p[t + 256 * i];
        s += v.x + v.y + v.z + v.w;
        m = fmaxf(m, fmaxf(fmaxf(v.x, v.y), fmaxf(v.z, v.w)));
    }
    for (int off = 32; off; off >>= 1) {
        s += __shfl_down(s, off);
        m = fmaxf(m, __shfl_down(m, off));
    }
    __shared__ float ss[4], sm[4];
    int wid = t >> 6;
    if ((t & 63) == 0) { ss[wid] = s; sm[wid] = m; }
    __syncthreads();
    if (t == 0) {
        float S = ss[0] + ss[1] + ss[2] + ss[3];
        float M = fmaxf(fmaxf(sm[0], sm[1]), fmaxf(sm[2], sm[3]));
        avgp[bc] = S * (1.f / (float)HWN);
        maxp[bc] = M;
    }
}

// ---------------- K2: SE gate ----------------
__global__ __launch_bounds__(256) void k_gate(const float* __restrict__ avgp,
                                              const float* __restrict__ maxp,
                                              const float* __restrict__ w1,
                                              const float* __restrict__ w2,
                                              float* __restrict__ gate) {
    int b = blockIdx.x, t = threadIdx.x;
    __shared__ float sa[CCH], sx[CCH], sh[32];
    sa[t] = avgp[b * CCH + t];
    sx[t] = maxp[b * CCH + t];
    __syncthreads();
    if (t < 32) {
        int r = t & 15;
        const float* src = (t < 16) ? sa : sx;
        float h = 0.f;
        for (int c = 0; c < CCH; ++c) h += w1[r * CCH + c] * src[c];
        sh[t] = fmaxf(h, 0.f);
    }
    __syncthreads();
    float g = 0.f;
#pragma unroll
    for (int r = 0; r < RR; ++r) g += w2[t * RR + r] * (sh[r] + sh[16 + r]);
    gate[b * CCH + t] = 1.f / (1.f + __expf(-g));
}

// ---------------- K-proj: fused q,k,v projections via bf16 MFMA ----------------
// vB in CHUNKED layout, natural j order: vB[b][jc][c][jo], jc = j>>3, jo = j&7.
__global__ __launch_bounds__(256) void k_proj(const float* __restrict__ x,
                                              const float* __restrict__ gate,
                                              const unsigned short* __restrict__ Wb,
                                              const float* __restrict__ vb,
                                              const float* __restrict__ qb,
                                              const float* __restrict__ kb,
                                              unsigned short* __restrict__ qT,
                                              unsigned short* __restrict__ kT,
                                              unsigned short* __restrict__ vB) {
    int b = blockIdx.x & 7;              // XCD swizzle: batch <-> XCD
    int n0 = (blockIdx.x >> 3) << 6;
    int t = threadIdx.x;
    int w = t >> 6, l = t & 63, quad = l >> 4, ln = l & 15;

    __shared__ __align__(16) unsigned short xs_t[64][72];    // [n_local][c_local] bf16
    __shared__ __align__(16) unsigned short vtile[256 * 72]; // [m][n_local] bf16, stride 72
    __shared__ float qk_s[32][66];   // q rows 0..15, k rows 16..31 (fp32)

    const f32x4 zf = {0.f, 0.f, 0.f, 0.f};
    f32x4 acc[18];
#pragma unroll
    for (int mt = 0; mt < 18; ++mt) acc[mt] = zf;

    for (int cc = 0; cc < 4; ++cc) {
        __syncthreads();
#pragma unroll
        for (int it = 0; it < 4; ++it) {
            int idx = it * 256 + t;
            int cl = idx >> 4, nq = idx & 15;
            int c = cc * 64 + cl;
            float g = gate[b * CCH + c];
            float4 v = *(const float4*)(x + (((size_t)(b * CCH + c)) << 12) + n0 + nq * 4);
            xs_t[nq * 4 + 0][cl] = f2bf(v.x * g);
            xs_t[nq * 4 + 1][cl] = f2bf(v.y * g);
            xs_t[nq * 4 + 2][cl] = f2bf(v.z * g);
            xs_t[nq * 4 + 3][cl] = f2bf(v.w * g);
        }
        __syncthreads();

        short8 bfrag[2];
#pragma unroll
        for (int kc = 0; kc < 2; ++kc)
            bfrag[kc] = *(const short8*)&xs_t[w * 16 + ln][kc * 32 + quad * 8];

#pragma unroll
        for (int mt = 0; mt < 18; ++mt) {
#pragma unroll
            for (int kc = 0; kc < 2; ++kc) {
                short8 af = *(const short8*)(Wb + ((size_t)(mt * 16 + ln)) * 256 + cc * 64 + kc * 32 + quad * 8);
                acc[mt] = __builtin_amdgcn_mfma_f32_16x16x32_bf16(af, bfrag[kc], acc[mt], 0, 0, 0);
            }
        }
    }

    // v rows -> vtile[m][n_local]
#pragma unroll
    for (int mt = 0; mt < 16; ++mt) {
#pragma unroll
        for (int r = 0; r < 4; ++r) {
            int m = mt * 16 + quad * 4 + r;
            vtile[m * 72 + w * 16 + ln] = f2bf(acc[mt][r] + vb[m]);
        }
    }
    // q/k -> LDS for transpose
#pragma unroll
    for (int r = 0; r < 4; ++r) {
        qk_s[quad * 4 + r][w * 16 + ln] = acc[16][r];
        qk_s[16 + quad * 4 + r][w * 16 + ln] = acc[17][r];
    }
    __syncthreads();

    // stream vtile -> vB chunks: thread t = c; 8 x 16B stores, 1KB coalesced segments
    {
        unsigned short* vBp = vB + (((size_t)b) << 20);
        int c = t;
#pragma unroll
        for (int Q = 0; Q < 8; ++Q) {
            short8 v8 = *(const short8*)(vtile + c * 72 + Q * 8);
            *(short8*)(vBp + ((size_t)((((n0 >> 3) + Q) << 8) + c) << 3)) = v8;
        }
    }
    if (t < 128) {
        int isK = t >> 6;
        int n = t & 63;
        const float* bias = isK ? kb : qb;
        unsigned u32[8];
#pragma unroll
        for (int j = 0; j < 8; ++j) {
            unsigned lo = f2bf(qk_s[isK * 16 + 2 * j][n] + bias[2 * j]);
            unsigned hi = f2bf(qk_s[isK * 16 + 2 * j + 1][n] + bias[2 * j + 1]);
            u32[j] = lo | (hi << 16);
        }
        unsigned short* dst = (isK ? kT : qT) + ((size_t)(b * HWN + n0 + n)) * RR;
        uint4 d0 = {u32[0], u32[1], u32[2], u32[3]};
        uint4 d1 = {u32[4], u32[5], u32[6], u32[7]};
        ((uint4*)dst)[0] = d0;
        ((uint4*)dst)[1] = d1;
    }
}

// ---------------- K-attn: MFMA flash attention (R7 structure + PSTR=68 conflict fix) ------
// R7 = measured best (123us): block (b XCD-swizzled, 32-i tile), 512 thr = 8 waves,
// grid 8x128=1024 (4 blocks/CU worth, 2 resident rotating). Wave w: S^T for
// (isub=w&1, jsub=w>>1) 16x16 tile, ONE MFMA (A=K, B=Q, d zero-padded to K=32);
// PV c-range w*32, 8 MFMAs. V+K register-dbuf, prefetch after barrier (full-step gap).
// R8 (i16) blew L2; R9 (i64, 18 MFMA/wave-step) doubled the serial chain - both regressed.
// Only change vs R7: PSTR 72 -> 68 (1.05e7 conflicts -> 0, measured R5/R9).
__global__ __launch_bounds__(512, 4) void k_attn(const unsigned short* __restrict__ qT,
                                                 const unsigned short* __restrict__ kT,
                                                 const unsigned short* __restrict__ vB,
                                                 const float* __restrict__ x,
                                                 const float* __restrict__ gate,
                                                 const float* __restrict__ gamma,
                                                 float* __restrict__ out) {
    int b = blockIdx.x & 7;
    int i0 = (blockIdx.x >> 3) << 5;     // 32-i tile
    int t = threadIdx.x;
    int w = t >> 6, l = t & 63;
    int quad = l >> 4, ln = l & 15;
    int isub = w & 1, jsub = w >> 1;
    int c0 = w * 32;

    __shared__ __align__(16) unsigned short p_lds[2][32 * PSTR];
    __shared__ float l_s[4][36];

    const short8 zs = {0, 0, 0, 0, 0, 0, 0, 0};
    const f32x4 zf = {0.f, 0.f, 0.f, 0.f};

    // persistent Q B-frag: B[k=d=quad*8+kk][n=i=ln] (quads 2,3 zero-pad d 16..31)
    short8 bq = zs;
    if (quad < 2)
        bq = *(const short8*)(qT + (((size_t)(b * HWN + i0 + isub * 16 + ln)) << 4) + (quad << 3));

    f32x4 acc[2][2];   // [cs][is]
#pragma unroll
    for (int cs = 0; cs < 2; ++cs)
#pragma unroll
        for (int is = 0; is < 2; ++is) acc[cs][is] = zf;
    float lsum = 0.f;

    const float c1 = 1.44269504f;      // log2(e)
    const float c0e = -11.5415603f;    // -8*log2(e): fixed shift, cancels in p/l

    const unsigned short* vbase = vB + (((size_t)b) << 20) + ((size_t)c0 << 3);
    const unsigned short* kbase = kT + ((size_t)(b * HWN)) * RR;

    // hoisted LDS offsets (PSTR=68 pattern, measured conflict-free)
    int soff = (isub * 16 + ln) * PSTR + jsub * 16 + quad * 4;   // uint2 store
    int roff0 = 0 * 16 * PSTR + ln * PSTR;                        // base for is=0 reads
    // (reads computed inline below, same form as R5/R9: (is*16+ln)*PSTR + ks*32 + quad*8)
    (void)roff0;

    short8 akA = zs, akB = zs;          // K A-frag dbuf: A[m=j=ln][k=d]
    short8 avA[4], avB[4];              // V A-frag dbuf: [ks*2+cs]

    auto load_ak = [&](short8& ak, int j0) {
        if (quad < 2)
            ak = *(const short8*)(kbase + (((size_t)(j0 + jsub * 16 + ln)) << 4) + (quad << 3));
    };
    auto load_av = [&](short8 (&av)[4], int j0) {
#pragma unroll
        for (int ks = 0; ks < 2; ++ks)
#pragma unroll
            for (int cs = 0; cs < 2; ++cs) {
                int jc = (j0 >> 3) + ks * 4 + quad;
                av[ks * 2 + cs] = *(const short8*)(vbase + ((size_t)(((jc << 8) + cs * 16 + ln)) << 3));
            }
    };

    load_ak(akA, 0);
    load_av(avA, 0);

    auto step = [&](short8& akC, short8 (&avC)[4], short8& akN, short8 (&avN)[4],
                    unsigned short* pbuf, int j0n, bool pf) {
        // S^T: C[row = j_local = quad*4+r][col = i = ln]
        f32x4 sf = __builtin_amdgcn_mfma_f32_16x16x32_bf16(akC, bq, zf, 0, 0, 0);

        float p0 = exp2f(fmaf(sf[0], c1, c0e));
        float p1 = exp2f(fmaf(sf[1], c1, c0e));
        float p2 = exp2f(fmaf(sf[2], c1, c0e));
        float p3 = exp2f(fmaf(sf[3], c1, c0e));
        lsum += (p0 + p1) + (p2 + p3);
        uint2 pk;
        pk.x = (bfr(p0) >> 16) | (bfr(p1) & 0xFFFF0000u);
        pk.y = (bfr(p2) >> 16) | (bfr(p3) & 0xFFFF0000u);
        *(uint2*)(pbuf + soff) = pk;

        __syncthreads();   // P(buf) visible; prev-step prefetches drained

        // next-step V/K issued HERE: drained at next barrier, a full step later
        if (pf) { load_ak(akN, j0n); load_av(avN, j0n); }

        // PV: A = V[c][j], B = P[j][i] (b128 contiguous rows)
#pragma unroll
        for (int ks = 0; ks < 2; ++ks) {
            short8 bp[2];
#pragma unroll
            for (int is = 0; is < 2; ++is)
                bp[is] = *(const short8*)(pbuf + (is * 16 + ln) * PSTR + ks * 32 + quad * 8);
#pragma unroll
            for (int cs = 0; cs < 2; ++cs)
#pragma unroll
                for (int is = 0; is < 2; ++is)
                    acc[cs][is] = __builtin_amdgcn_mfma_f32_16x16x32_bf16(avC[ks * 2 + cs], bp[is], acc[cs][is], 0, 0, 0);
        }
    };

    for (int jt2 = 0; jt2 < 32; ++jt2) {
        int j0 = jt2 << 7;
        step(akA, avA, akB, avB, &p_lds[0][0], j0 + 64, true);
        step(akB, avB, akA, avA, &p_lds[1][0], (jt2 < 31) ? (j0 + 128) : 0, jt2 < 31);
    }

    // l reduction: lane's lsum covers its 4 j's (one i = isub*16+ln per lane-column)
    lsum += __shfl_xor(lsum, 16, 64);
    lsum += __shfl_xor(lsum, 32, 64);
    if (l < 16) l_s[jsub][isub * 16 + l] = lsum;
    __syncthreads();

    float g = gamma[0];
    float rinv[2];
#pragma unroll
    for (int is = 0; is < 2; ++is) {
        int i = is * 16 + ln;
        float lf = (l_s[0][i] + l_s[1][i]) + (l_s[2][i] + l_s[3][i]);
        rinv[is] = g / lf;
    }

    // epilogue: out = gamma*o/l + x*gate
#pragma unroll
    for (int cs = 0; cs < 2; ++cs) {
#pragma unroll
        for (int r = 0; r < 4; ++r) {
            int c = c0 + cs * 16 + quad * 4 + r;
            float gc = gate[b * CCH + c];
            size_t rowoff = (((size_t)(b * CCH + c)) << 12) + i0;
            float* po = out + rowoff;
            const float* px = x + rowoff;
#pragma unroll
            for (int is = 0; is < 2; ++is) {
                int idx = is * 16 + ln;
                po[idx] = acc[cs][is][r] * rinv[is] + px[idx] * gc;
            }
        }
    }
}

extern "C" void kernel_launch(void* const* d_in, const int* in_sizes, int n_in,
                              void* d_out, int out_size, void* d_ws, size_t ws_size,
                              hipStream_t stream) {
    const float* x = (const float*)d_in[0];
    const float* w1 = (const float*)d_in[1];
    const float* w2 = (const float*)d_in[2];
    const float* qw = (const float*)d_in[3];
    const float* qb = (const float*)d_in[4];
    const float* kw = (const float*)d_in[5];
    const float* kb = (const float*)d_in[6];
    const float* vw = (const float*)d_in[7];
    const float* vb = (const float*)d_in[8];
    const float* gamma = (const float*)d_in[9];
    float* out = (float*)d_out;
    char* ws = (char*)d_ws;

    float* avgp = (float*)(ws);                        // 8 KB
    float* maxp = (float*)(ws + 8192);                 // 8 KB
    float* gate = (float*)(ws + 16384);                // 8 KB
    unsigned short* Wb = (unsigned short*)(ws + 24576);               // [288][256] bf16
    unsigned short* qT = (unsigned short*)(ws + 24576 + 147456);      // 1 MB [b][n][16]
    unsigned short* kT = (unsigned short*)(ws + 24576 + 147456 + 1048576);
    unsigned short* vB = (unsigned short*)(ws + 24576 + 147456 + 2097152);  // 16.8 MB chunked

    k_pool<<<2048, 256, 0, stream>>>(x, avgp, maxp, vw, qw, kw, Wb);  // + fused wprep
    k_gate<<<8, 256, 0, stream>>>(avgp, maxp, w1, w2, gate);
    k_proj<<<512, 256, 0, stream>>>(x, gate, Wb, vb, qb, kb, qT, kT, vB);
    k_attn<<<1024, 512, 0, stream>>>(qT, kT, vB, x, gate, gamma, out);
}

// Round 11
// 251.929 us; speedup vs baseline: 2.2122x; 1.5398x over previous
//
#include <hip/hip_runtime.h>
#include <hip/hip_bf16.h>
#include <math.h>

#define BB 8
#define CCH 256
#define HWN 4096
#define RR 16

typedef __attribute__((ext_vector_type(8))) short short8;   // 8 bf16 = K=32 MFMA A/B frag (4 VGPRs)
typedef __attribute__((ext_vector_type(4))) float f32x4;    // MFMA C/D frag

static __device__ __forceinline__ unsigned short f2bf(float x) {
    union { float f; unsigned u; } v; v.f = x;
    return (unsigned short)((v.u + 0x8000u) >> 16);   // round-half-up bf16
}
static __device__ __forceinline__ unsigned bfr(float x) {   // bits + rounding offset
    union { float f; unsigned u; } v; v.f = x;
    return v.u + 0x8000u;
}

// ---------------- K1: avg+max pool per (b,c); blocks 0..287 also pack Wb (fused wprep) ----
__global__ __launch_bounds__(256) void k_pool(const float* __restrict__ x,
                                              float* __restrict__ avgp,
                                              float* __restrict__ maxp,
                                              const float* __restrict__ vw,
                                              const float* __restrict__ qw,
                                              const float* __restrict__ kw,
                                              unsigned short* __restrict__ Wb) {
    int bc = blockIdx.x;
    int t = threadIdx.x;
    if (bc < 288) {
        int idx = bc * 256 + t;
        int m = idx >> 8, c = idx & 255;
        float v;
        if (m < 256) v = vw[idx];
        else if (m < 272) v = qw[(m - 256) * 256 + c];
        else v = kw[(m - 272) * 256 + c];
        Wb[idx] = f2bf(v);
    }
    const float4* p = (const float4*)(x + (size_t)bc * HWN);
    float s = 0.f, m = -INFINITY;
#pragma unroll
    for (int i = 0; i < 4; ++i) {
        float4 v = p[t + 256 * i];
        s += v.x + v.y + v.z + v.w;
        m = fmaxf(m, fmaxf(fmaxf(v.x, v.y), fmaxf(v.z, v.w)));
    }
    for (int off = 32; off; off >>= 1) {
        s += __shfl_down(s, off);
        m = fmaxf(m, __shfl_down(m, off));
    }
    __shared__ float ss[4], sm[4];
    int wid = t >> 6;
    if ((t & 63) == 0) { ss[wid] = s; sm[wid] = m; }
    __syncthreads();
    if (t == 0) {
        float S = ss[0] + ss[1] + ss[2] + ss[3];
        float M = fmaxf(fmaxf(sm[0], sm[1]), fmaxf(sm[2], sm[3]));
        avgp[bc] = S * (1.f / (float)HWN);
        maxp[bc] = M;
    }
}

// ---------------- K2: SE gate ----------------
__global__ __launch_bounds__(256) void k_gate(const float* __restrict__ avgp,
                                              const float* __restrict__ maxp,
                                              const float* __restrict__ w1,
                                              const float* __restrict__ w2,
                                              float* __restrict__ gate) {
    int b = blockIdx.x, t = threadIdx.x;
    __shared__ float sa[CCH], sx[CCH], sh[32];
    sa[t] = avgp[b * CCH + t];
    sx[t] = maxp[b * CCH + t];
    __syncthreads();
    if (t < 32) {
        int r = t & 15;
        const float* src = (t < 16) ? sa : sx;
        float h = 0.f;
        for (int c = 0; c < CCH; ++c) h += w1[r * CCH + c] * src[c];
        sh[t] = fmaxf(h, 0.f);
    }
    __syncthreads();
    float g = 0.f;
#pragma unroll
    for (int r = 0; r < RR; ++r) g += w2[t * RR + r] * (sh[r] + sh[16 + r]);
    gate[b * CCH + t] = 1.f / (1.f + __expf(-g));
}

// ---------------- K-proj: fused q,k,v projections via bf16 MFMA (R7-identical) ----------
// vB in CHUNKED layout, natural j order: vB[b][jc][c][jo], jc = j>>3, jo = j&7.
__global__ __launch_bounds__(256) void k_proj(const float* __restrict__ x,
                                              const float* __restrict__ gate,
                                              const unsigned short* __restrict__ Wb,
                                              const float* __restrict__ vb,
                                              const float* __restrict__ qb,
                                              const float* __restrict__ kb,
                                              unsigned short* __restrict__ qT,
                                              unsigned short* __restrict__ kT,
                                              unsigned short* __restrict__ vB) {
    int b = blockIdx.x & 7;              // XCD swizzle: batch <-> XCD
    int n0 = (blockIdx.x >> 3) << 6;
    int t = threadIdx.x;
    int w = t >> 6, l = t & 63, quad = l >> 4, ln = l & 15;

    __shared__ __align__(16) unsigned short xs_t[64][72];    // [n_local][c_local] bf16
    __shared__ __align__(16) unsigned short vtile[256 * 72]; // [m][n_local] bf16, stride 72
    __shared__ float qk_s[32][66];   // q rows 0..15, k rows 16..31 (fp32)

    const f32x4 zf = {0.f, 0.f, 0.f, 0.f};
    f32x4 acc[18];
#pragma unroll
    for (int mt = 0; mt < 18; ++mt) acc[mt] = zf;

    for (int cc = 0; cc < 4; ++cc) {
        __syncthreads();
#pragma unroll
        for (int it = 0; it < 4; ++it) {
            int idx = it * 256 + t;
            int cl = idx >> 4, nq = idx & 15;
            int c = cc * 64 + cl;
            float g = gate[b * CCH + c];
            float4 v = *(const float4*)(x + (((size_t)(b * CCH + c)) << 12) + n0 + nq * 4);
            xs_t[nq * 4 + 0][cl] = f2bf(v.x * g);
            xs_t[nq * 4 + 1][cl] = f2bf(v.y * g);
            xs_t[nq * 4 + 2][cl] = f2bf(v.z * g);
            xs_t[nq * 4 + 3][cl] = f2bf(v.w * g);
        }
        __syncthreads();

        short8 bfrag[2];
#pragma unroll
        for (int kc = 0; kc < 2; ++kc)
            bfrag[kc] = *(const short8*)&xs_t[w * 16 + ln][kc * 32 + quad * 8];

#pragma unroll
        for (int mt = 0; mt < 18; ++mt) {
#pragma unroll
            for (int kc = 0; kc < 2; ++kc) {
                short8 af = *(const short8*)(Wb + ((size_t)(mt * 16 + ln)) * 256 + cc * 64 + kc * 32 + quad * 8);
                acc[mt] = __builtin_amdgcn_mfma_f32_16x16x32_bf16(af, bfrag[kc], acc[mt], 0, 0, 0);
            }
        }
    }

    // v rows -> vtile[m][n_local]
#pragma unroll
    for (int mt = 0; mt < 16; ++mt) {
#pragma unroll
        for (int r = 0; r < 4; ++r) {
            int m = mt * 16 + quad * 4 + r;
            vtile[m * 72 + w * 16 + ln] = f2bf(acc[mt][r] + vb[m]);
        }
    }
    // q/k -> LDS for transpose
#pragma unroll
    for (int r = 0; r < 4; ++r) {
        qk_s[quad * 4 + r][w * 16 + ln] = acc[16][r];
        qk_s[16 + quad * 4 + r][w * 16 + ln] = acc[17][r];
    }
    __syncthreads();

    // stream vtile -> vB chunks: thread t = c; 8 x 16B stores, 1KB coalesced segments
    {
        unsigned short* vBp = vB + (((size_t)b) << 20);
        int c = t;
#pragma unroll
        for (int Q = 0; Q < 8; ++Q) {
            short8 v8 = *(const short8*)(vtile + c * 72 + Q * 8);
            *(short8*)(vBp + ((size_t)((((n0 >> 3) + Q) << 8) + c) << 3)) = v8;
        }
    }
    if (t < 128) {
        int isK = t >> 6;
        int n = t & 63;
        const float* bias = isK ? kb : qb;
        unsigned u32[8];
#pragma unroll
        for (int j = 0; j < 8; ++j) {
            unsigned lo = f2bf(qk_s[isK * 16 + 2 * j][n] + bias[2 * j]);
            unsigned hi = f2bf(qk_s[isK * 16 + 2 * j + 1][n] + bias[2 * j + 1]);
            u32[j] = lo | (hi << 16);
        }
        unsigned short* dst = (isK ? kT : qT) + ((size_t)(b * HWN + n0 + n)) * RR;
        uint4 d0 = {u32[0], u32[1], u32[2], u32[3]};
        uint4 d1 = {u32[4], u32[5], u32[6], u32[7]};
        ((uint4*)dst)[0] = d0;
        ((uint4*)dst)[1] = d1;
    }
}

// ---------------- K-attn: MFMA flash attention (R7 champion + chunk-major P LDS) ---------
// R7 structure verbatim (123us measured): block (b XCD-swizzled, 32-i tile), 512 thr =
// 8 waves, grid 1024. Wave w: S^T for (isub=w&1, jsub=w>>1) 16x16, ONE MFMA (A=K, B=Q);
// PV c-range w*32, 8 MFMAs; V+K register-dbuf, prefetch after barrier.
// P LDS layout: chunk-major offset(i,j) = ((j/8)*32 + i)*8 + j%8 (4KB/buf).
//   - b128 read: 16B-ALIGNED (R10 lesson: 8-mod-16 alignment = 2.6x slowdown)
//   - read banks: 4*ln mod 32 -> uniform 2-way = FREE (m136); hits 8cy/1024B BW floor
//   - store banks: 4ln+2(quad&1)+d -> uniform 4-way = 4cy/512B BW floor
// (R7's PSTR=72 reads concentrated 64 lanes on 8 banks/phase -> its 1.05e7 conflicts.)
__global__ __launch_bounds__(512, 4) void k_attn(const unsigned short* __restrict__ qT,
                                                 const unsigned short* __restrict__ kT,
                                                 const unsigned short* __restrict__ vB,
                                                 const float* __restrict__ x,
                                                 const float* __restrict__ gate,
                                                 const float* __restrict__ gamma,
                                                 float* __restrict__ out) {
    int b = blockIdx.x & 7;
    int i0 = (blockIdx.x >> 3) << 5;     // 32-i tile
    int t = threadIdx.x;
    int w = t >> 6, l = t & 63;
    int quad = l >> 4, ln = l & 15;
    int isub = w & 1, jsub = w >> 1;
    int c0 = w * 32;

    __shared__ __align__(16) unsigned short p_lds[2][2048];   // chunk-major, 4KB each
    __shared__ float l_s[4][36];

    const short8 zs = {0, 0, 0, 0, 0, 0, 0, 0};
    const f32x4 zf = {0.f, 0.f, 0.f, 0.f};

    // persistent Q B-frag: B[k=d=quad*8+kk][n=i=ln] (quads 2,3 zero-pad d 16..31)
    short8 bq = zs;
    if (quad < 2)
        bq = *(const short8*)(qT + (((size_t)(b * HWN + i0 + isub * 16 + ln)) << 4) + (quad << 3));

    f32x4 acc[2][2];   // [cs][is]
#pragma unroll
    for (int cs = 0; cs < 2; ++cs)
#pragma unroll
        for (int is = 0; is < 2; ++is) acc[cs][is] = zf;
    float lsum = 0.f;

    const float c1 = 1.44269504f;      // log2(e)
    const float c0e = -11.5415603f;    // -8*log2(e): fixed shift, cancels in p/l

    const unsigned short* vbase = vB + (((size_t)b) << 20) + ((size_t)c0 << 3);
    const unsigned short* kbase = kT + ((size_t)(b * HWN)) * RR;

    // hoisted chunk-major LDS offsets (ushort units)
    // store: i = isub*16+ln, j-chunk = jsub*2 + (quad>>1), j%8 = (quad&1)*4
    int soff = ((jsub * 2 + (quad >> 1)) * 32 + isub * 16 + ln) * 8 + (quad & 1) * 4;
    // read: chunk = ks*4 + quad, i = is*16 + ln  -> base + ks*1024 + is*128
    int rbase = quad * 256 + ln * 8;

    short8 akA = zs, akB = zs;          // K A-frag dbuf: A[m=j=ln][k=d]
    short8 avA[4], avB[4];              // V A-frag dbuf: [ks*2+cs]

    auto load_ak = [&](short8& ak, int j0) {
        if (quad < 2)
            ak = *(const short8*)(kbase + (((size_t)(j0 + jsub * 16 + ln)) << 4) + (quad << 3));
    };
    auto load_av = [&](short8 (&av)[4], int j0) {
#pragma unroll
        for (int ks = 0; ks < 2; ++ks)
#pragma unroll
            for (int cs = 0; cs < 2; ++cs) {
                int jc = (j0 >> 3) + ks * 4 + quad;
                av[ks * 2 + cs] = *(const short8*)(vbase + ((size_t)(((jc << 8) + cs * 16 + ln)) << 3));
            }
    };

    load_ak(akA, 0);
    load_av(avA, 0);

    auto step = [&](short8& akC, short8 (&avC)[4], short8& akN, short8 (&avN)[4],
                    unsigned short* pbuf, int j0n, bool pf) {
        // S^T: C[row = j_local = quad*4+r][col = i = ln]
        f32x4 sf = __builtin_amdgcn_mfma_f32_16x16x32_bf16(akC, bq, zf, 0, 0, 0);

        float p0 = exp2f(fmaf(sf[0], c1, c0e));
        float p1 = exp2f(fmaf(sf[1], c1, c0e));
        float p2 = exp2f(fmaf(sf[2], c1, c0e));
        float p3 = exp2f(fmaf(sf[3], c1, c0e));
        lsum += (p0 + p1) + (p2 + p3);
        uint2 pk;
        pk.x = (bfr(p0) >> 16) | (bfr(p1) & 0xFFFF0000u);
        pk.y = (bfr(p2) >> 16) | (bfr(p3) & 0xFFFF0000u);
        *(uint2*)(pbuf + soff) = pk;

        __syncthreads();   // P(buf) visible; prev-step prefetches drained

        // next-step V/K issued HERE: drained at next barrier, a full step later
        if (pf) { load_ak(akN, j0n); load_av(avN, j0n); }

        // PV: A = V[c][j], B = P^T[j][i] (16B-aligned chunk reads, 2-way-free banks)
#pragma unroll
        for (int ks = 0; ks < 2; ++ks) {
            short8 bp[2];
#pragma unroll
            for (int is = 0; is < 2; ++is)
                bp[is] = *(const short8*)(pbuf + rbase + ks * 1024 + is * 128);
#pragma unroll
            for (int cs = 0; cs < 2; ++cs)
#pragma unroll
                for (int is = 0; is < 2; ++is)
                    acc[cs][is] = __builtin_amdgcn_mfma_f32_16x16x32_bf16(avC[ks * 2 + cs], bp[is], acc[cs][is], 0, 0, 0);
        }
    };

    for (int jt2 = 0; jt2 < 32; ++jt2) {
        int j0 = jt2 << 7;
        step(akA, avA, akB, avB, &p_lds[0][0], j0 + 64, true);
        step(akB, avB, akA, avA, &p_lds[1][0], (jt2 < 31) ? (j0 + 128) : 0, jt2 < 31);
    }

    // l reduction: lane's lsum covers its 4 j's (one i = isub*16+ln per lane-column)
    lsum += __shfl_xor(lsum, 16, 64);
    lsum += __shfl_xor(lsum, 32, 64);
    if (l < 16) l_s[jsub][isub * 16 + l] = lsum;
    __syncthreads();

    float g = gamma[0];
    float rinv[2];
#pragma unroll
    for (int is = 0; is < 2; ++is) {
        int i = is * 16 + ln;
        float lf = (l_s[0][i] + l_s[1][i]) + (l_s[2][i] + l_s[3][i]);
        rinv[is] = g / lf;
    }

    // epilogue: out = gamma*o/l + x*gate
#pragma unroll
    for (int cs = 0; cs < 2; ++cs) {
#pragma unroll
        for (int r = 0; r < 4; ++r) {
            int c = c0 + cs * 16 + quad * 4 + r;
            float gc = gate[b * CCH + c];
            size_t rowoff = (((size_t)(b * CCH + c)) << 12) + i0;
            float* po = out + rowoff;
            const float* px = x + rowoff;
#pragma unroll
            for (int is = 0; is < 2; ++is) {
                int idx = is * 16 + ln;
                po[idx] = acc[cs][is][r] * rinv[is] + px[idx] * gc;
            }
        }
    }
}

extern "C" void kernel_launch(void* const* d_in, const int* in_sizes, int n_in,
                              void* d_out, int out_size, void* d_ws, size_t ws_size,
                              hipStream_t stream) {
    const float* x = (const float*)d_in[0];
    const float* w1 = (const float*)d_in[1];
    const float* w2 = (const float*)d_in[2];
    const float* qw = (const float*)d_in[3];
    const float* qb = (const float*)d_in[4];
    const float* kw = (const float*)d_in[5];
    const float* kb = (const float*)d_in[6];
    const float* vw = (const float*)d_in[7];
    const float* vb = (const float*)d_in[8];
    const float* gamma = (const float*)d_in[9];
    float* out = (float*)d_out;
    char* ws = (char*)d_ws;

    float* avgp = (float*)(ws);                        // 8 KB
    float* maxp = (float*)(ws + 8192);                 // 8 KB
    float* gate = (float*)(ws + 16384);                // 8 KB
    unsigned short* Wb = (unsigned short*)(ws + 24576);               // [288][256] bf16
    unsigned short* qT = (unsigned short*)(ws + 24576 + 147456);      // 1 MB [b][n][16]
    unsigned short* kT = (unsigned short*)(ws + 24576 + 147456 + 1048576);
    unsigned short* vB = (unsigned short*)(ws + 24576 + 147456 + 2097152);  // 16.8 MB chunked

    k_pool<<<2048, 256, 0, stream>>>(x, avgp, maxp, vw, qw, kw, Wb);  // + fused wprep
    k_gate<<<8, 256, 0, stream>>>(avgp, maxp, w1, w2, gate);
    k_proj<<<512, 256, 0, stream>>>(x, gate, Wb, vb, qb, kb, qT, kT, vB);
    k_attn<<<1024, 512, 0, stream>>>(qT, kT, vB, x, gate, gamma, out);
}